// Round 12
// baseline (9634.859 us; speedup 1.0000x reference)
//
#include <hip/hip_runtime.h>
#include <hip/hip_bf16.h>
#include <stdint.h>
#include <math.h>

#define BB   8192
#define EE   1024
#define GG   4096
#define TTK  64
#define LLEN 20

#define PRNG_PARTITIONABLE 1

typedef __attribute__((ext_vector_type(8)))  __bf16 bf16x8;
typedef __attribute__((ext_vector_type(4)))  __bf16 bf16x4;
typedef __attribute__((ext_vector_type(16))) float  f32x16;

// ---------------- Threefry-2x32 ----------------
__host__ __device__ __forceinline__ void tf2x32(unsigned k0, unsigned k1,
                                                unsigned x0, unsigned x1,
                                                unsigned& o0, unsigned& o1) {
  unsigned ks2 = k0 ^ k1 ^ 0x1BD11BDAu;
#define TFR(r) { x0 += x1; x1 = (x1 << (r)) | (x1 >> (32 - (r))); x1 ^= x0; }
  x0 += k0; x1 += k1;
  TFR(13) TFR(15) TFR(26) TFR(6)  x0 += k1;  x1 += ks2 + 1u;
  TFR(17) TFR(29) TFR(16) TFR(24) x0 += ks2; x1 += k0 + 2u;
  TFR(13) TFR(15) TFR(26) TFR(6)  x0 += k0;  x1 += k1 + 3u;
  TFR(17) TFR(29) TFR(16) TFR(24) x0 += k1;  x1 += ks2 + 4u;
  TFR(13) TFR(15) TFR(26) TFR(6)  x0 += ks2; x1 += k0 + 5u;
#undef TFR
  o0 = x0; o1 = x1;
}

// ---------------- wave-64 reductions ----------------
__device__ __forceinline__ float wave_max64(float v) {
#pragma unroll
  for (int o = 32; o > 0; o >>= 1) v = fmaxf(v, __shfl_xor(v, o));
  return v;
}
__device__ __forceinline__ float wave_sum64(float v) {
#pragma unroll
  for (int o = 32; o > 0; o >>= 1) v += __shfl_xor(v, o);
  return v;
}
__device__ __forceinline__ void wave_argmax64(float v, int i, float& rv, int& ri) {
  rv = v; ri = i;
#pragma unroll
  for (int o = 32; o > 0; o >>= 1) {
    float ov = __shfl_xor(rv, o);
    int   oi = __shfl_xor(ri, o);
    if (ov > rv || (ov == rv && oi < ri)) { rv = ov; ri = oi; }
  }
}

// global -> LDS direct DMA, 16B per lane
__device__ __forceinline__ void gl16(const __bf16* g, __bf16* l) {
  __builtin_amdgcn_global_load_lds(
      (const __attribute__((address_space(1))) void*)g,
      (__attribute__((address_space(3))) void*)l, 16, 0, 0);
}

// ---------------- fp32 -> 3x bf16 split ----------------
__global__ void split3_kernel(const float* __restrict__ in, __bf16* __restrict__ s0,
                              __bf16* __restrict__ s1, __bf16* __restrict__ s2, int n) {
  int i = blockIdx.x * blockDim.x + threadIdx.x;
  int stride = gridDim.x * blockDim.x;
  for (; i < n; i += stride) {
    float x = in[i];
    __bf16 a = (__bf16)x; float r1 = x - (float)a;
    __bf16 b = (__bf16)r1; float r2 = r1 - (float)b;
    s0[i] = a; s1[i] = b; s2[i] = (__bf16)r2;
  }
}

// ---------------- embW[t][j] = dot(emb[t], W_ih[j]) + b_ih[j] ----------------
__global__ __launch_bounds__(256)
void embw_kernel(const float* __restrict__ emb, const float* __restrict__ Wih,
                 const float* __restrict__ bih, float* __restrict__ embW,
                 float* __restrict__ ent_acc, int* __restrict__ match_acc) {
  if (blockIdx.x == 0 && threadIdx.x == 0) { *ent_acc = 0.0f; *match_acc = 0; }
  __shared__ float hsm[64][36];
  __shared__ float wsm[64][65];
  const int j0 = blockIdx.x * 32;
  const int tid = threadIdx.x;
  const int wv = tid >> 6, lane = tid & 63;
  float acc[8];
#pragma unroll
  for (int r = 0; r < 8; r++) acc[r] = 0.0f;

  for (int k0 = 0; k0 < EE; k0 += 64) {
    {
      int row = tid >> 3, kb = (tid & 7) * 8;
      const float4* p = reinterpret_cast<const float4*>(Wih + (size_t)(j0 + row) * EE + k0 + kb);
      float4 v0 = p[0], v1 = p[1];
      hsm[kb + 0][row] = v0.x; hsm[kb + 1][row] = v0.y; hsm[kb + 2][row] = v0.z; hsm[kb + 3][row] = v0.w;
      hsm[kb + 4][row] = v1.x; hsm[kb + 5][row] = v1.y; hsm[kb + 6][row] = v1.z; hsm[kb + 7][row] = v1.w;
      int tr = tid >> 2, kc = (tid & 3) * 16;
      const float4* q = reinterpret_cast<const float4*>(emb + (size_t)tr * EE + k0 + kc);
#pragma unroll
      for (int i = 0; i < 4; i++) {
        float4 a = q[i];
        wsm[tr][kc + i * 4 + 0] = a.x; wsm[tr][kc + i * 4 + 1] = a.y;
        wsm[tr][kc + i * 4 + 2] = a.z; wsm[tr][kc + i * 4 + 3] = a.w;
      }
    }
    __syncthreads();
#pragma unroll
    for (int k = 0; k < 64; k++) {
      float w0 = wsm[lane][k];
      float4 va = *reinterpret_cast<const float4*>(&hsm[k][wv * 8]);
      float4 vb = *reinterpret_cast<const float4*>(&hsm[k][wv * 8 + 4]);
      acc[0] = fmaf(va.x, w0, acc[0]); acc[1] = fmaf(va.y, w0, acc[1]);
      acc[2] = fmaf(va.z, w0, acc[2]); acc[3] = fmaf(va.w, w0, acc[3]);
      acc[4] = fmaf(vb.x, w0, acc[4]); acc[5] = fmaf(vb.y, w0, acc[5]);
      acc[6] = fmaf(vb.z, w0, acc[6]); acc[7] = fmaf(vb.w, w0, acc[7]);
    }
    __syncthreads();
  }
#pragma unroll
  for (int r = 0; r < 8; r++) {
    int j = j0 + wv * 8 + r;
    embW[(size_t)lane * GG + j] = __fadd_rn(acc[r], bih[j]);
  }
}

// ---------------- MFMA LSTM step (bf16x3 fp32 emulation) ----------------
// BK=16 DOUBLE-BUFFERED pipeline at 2 blocks/CU (first config with both
// TLP and pipelining): per kt issue STAGE(kt+1 -> other buf), compute
// current, then vmcnt(0)+lgkm(0)+one raw barrier (the stage had the whole
// compute phase to land). Rows of 48 elems (6x16B chunks); bank-conflict
// fix via involution chunk_phys = chunk_log ^ ((row>>2)&1) applied on BOTH
// the DMA source decode and the read addresses (rule #21).
#define AST16  48      // elems per row (96 B = 6 chunks)
#define BUFE16 18432   // 384 rows x 48 elems per buffer (36,864 B)
__global__ __launch_bounds__(256, 2)
void lstm_mfma_kernel(const __bf16* __restrict__ hA0, const __bf16* __restrict__ hA1,
                      const __bf16* __restrict__ hA2,
                      __bf16* __restrict__ hN0, __bf16* __restrict__ hN1,
                      __bf16* __restrict__ hN2,
                      float* __restrict__ cbuf,
                      const __bf16* __restrict__ w0s, const __bf16* __restrict__ w1s,
                      const __bf16* __restrict__ w2s,
                      const float* __restrict__ embW, const float* __restrict__ bhh,
                      const int* __restrict__ tok, int step) {
  __shared__ __bf16 lds[2 * BUFE16];   // 73,728 B -> 2 blocks/CU
  unsigned bid = blockIdx.x;
  unsigned xcd = bid & 7, j0b = bid >> 3;      // (4m x 2n) XCD tiling
  unsigned xm = xcd >> 1, xn = xcd & 1;
  const int m = (int)(xm * 8 + (j0b & 7));
  const int n = (int)(xn * 16 + (j0b >> 3));
  const int row0 = m * 256, e0 = n * 32;
  const int tid = threadIdx.x;
  const int w = tid >> 6, l = tid & 63;

  f32x16 acc[2][4];
#pragma unroll
  for (int rt = 0; rt < 2; rt++)
#pragma unroll
    for (int ct = 0; ct < 4; ct++)
#pragma unroll
      for (int q = 0; q < 16; q++) acc[rt][ct][q] = 0.0f;

  // ---- DMA source decode: 2304 chunks (384 rows x 6), 9 per thread ----
  // chunk c -> row = c/6, phys chunk tp = c%6; logical t = tp ^ ((row>>2)&1);
  // t = s*2 + half. rows 0..255 = A (row0+row), 256..383 = B gate-cols.
  const __bf16* src[9];
#pragma unroll
  for (int i = 0; i < 9; i++) {
    int c = i * 256 + tid;
    int row = c / 6, tp = c - row * 6;
    int t = tp ^ ((row >> 2) & 1);
    int s = t >> 1, hf = t & 1;
    const __bf16* base; size_t off;
    if (row < 256) {
      base = (s == 0) ? hA0 : (s == 1) ? hA1 : hA2;
      off = (size_t)(row0 + row) * EE + hf * 8;
    } else {
      int c2 = row - 256;
      int jj = (c2 >> 5) * 1024 + e0 + (c2 & 31);
      base = (s == 0) ? w0s : (s == 1) ? w1s : w2s;
      off = (size_t)jj * EE + hf * 8;
    }
    src[i] = base + off;
  }
  const int dstT = tid * 8;   // chunk c dst = c*8 elems = i*2048 + tid*8

#define STAGE(BUF, KE) do {                                              \
    _Pragma("unroll")                                                    \
    for (int i_ = 0; i_ < 9; i_++)                                       \
      gl16(src[i_] + (KE), lds + (BUF) + i_ * 2048 + dstT);              \
  } while (0)

  // ---- read address precompute (swizzle bit = row bit2 = (l>>2)&1) ----
  const int li = l & 31, hf = l >> 5, sb = (l >> 2) & 1;
  int tps[3];
#pragma unroll
  for (int s = 0; s < 3; s++) tps[s] = ((s * 2 + hf) ^ sb) * 8;
  int aBase[2], bBase[4];
#pragma unroll
  for (int rt = 0; rt < 2; rt++) aBase[rt] = (w * 64 + rt * 32 + li) * AST16;
#pragma unroll
  for (int ct = 0; ct < 4; ct++) bBase[ct] = (256 + ct * 32 + li) * AST16;

  // prologue: stage K-tile 0 into buffer 0
  STAGE(0, 0);
  asm volatile("s_waitcnt vmcnt(0)" ::: "memory");
  __builtin_amdgcn_s_barrier();

  for (int kt = 0; kt < 64; ++kt) {
    const int cur = (kt & 1) * BUFE16;
    if (kt < 63) STAGE(cur ^ BUFE16, (kt + 1) * 16);   // prefetch next tile
    const __bf16* base = lds + cur;
    __builtin_amdgcn_s_setprio(1);
    bf16x8 a[2][3];
#pragma unroll
    for (int rt = 0; rt < 2; rt++)
#pragma unroll
      for (int s = 0; s < 3; s++)
        a[rt][s] = *(const bf16x8*)(base + aBase[rt] + tps[s]);
#pragma unroll
    for (int ct = 0; ct < 4; ct++) {
      bf16x8 b0 = *(const bf16x8*)(base + bBase[ct] + tps[0]);
      bf16x8 b1 = *(const bf16x8*)(base + bBase[ct] + tps[1]);
      bf16x8 b2 = *(const bf16x8*)(base + bBase[ct] + tps[2]);
#pragma unroll
      for (int rt = 0; rt < 2; rt++) {
        f32x16 t = acc[rt][ct];
        t = __builtin_amdgcn_mfma_f32_32x32x16_bf16(a[rt][2], b0, t, 0, 0, 0);
        t = __builtin_amdgcn_mfma_f32_32x32x16_bf16(a[rt][0], b2, t, 0, 0, 0);
        t = __builtin_amdgcn_mfma_f32_32x32x16_bf16(a[rt][1], b1, t, 0, 0, 0);
        t = __builtin_amdgcn_mfma_f32_32x32x16_bf16(a[rt][1], b0, t, 0, 0, 0);
        t = __builtin_amdgcn_mfma_f32_32x32x16_bf16(a[rt][0], b1, t, 0, 0, 0);
        t = __builtin_amdgcn_mfma_f32_32x32x16_bf16(a[rt][0], b0, t, 0, 0, 0);
        acc[rt][ct] = t;
      }
    }
    __builtin_amdgcn_s_setprio(0);
    // reads of cur retired + next-tile stage landed (hidden under MFMAs)
    asm volatile("s_waitcnt vmcnt(0) lgkmcnt(0)" ::: "memory");
    __builtin_amdgcn_s_barrier();
  }
#undef STAGE

  // ---- epilogue: LSTM cell, via per-wave LDS transpose patches ----
  float* eC = ((float*)lds) + w * 2112;   // [32][33]
  float* eH = eC + 1056;                  // [32][33]
  const int e_l = l & 31, half = l >> 5;
  float bh4[4];
#pragma unroll
  for (int g = 0; g < 4; g++) bh4[g] = bhh[g * 1024 + e0 + e_l];

#pragma unroll
  for (int rt = 0; rt < 2; rt++) {
    const int rowbase = row0 + w * 64 + rt * 32;
    // phase 1: stage c_old (coalesced) into LDS
    {
      int r = l >> 3, ch = l & 7;
#pragma unroll
      for (int q = 0; q < 4; q++) {
        float4 cv;
        if (step == 0) cv = make_float4(0.f, 0.f, 0.f, 0.f);
        else cv = *(const float4*)(cbuf + (size_t)(rowbase + r + q * 8) * EE + e0 + ch * 4);
        *(float4*)(eC + (r + q * 8) * 33 + ch * 4) = cv;
      }
    }
    __syncthreads();
    // phase 2: per-lane cell computation
#pragma unroll
    for (int i = 0; i < 16; i++) {
      int rl = (i & 3) + 8 * (i >> 2) + 4 * half;
      int b = rowbase + rl;
      int tk = (step == 0) ? 0 : tok[b];
      const float* er = embW + (size_t)tk * GG;
      float g0 = __fadd_rn(__fadd_rn(er[0 * 1024 + e0 + e_l], acc[rt][0][i]), bh4[0]);
      float g1 = __fadd_rn(__fadd_rn(er[1 * 1024 + e0 + e_l], acc[rt][1][i]), bh4[1]);
      float g2 = __fadd_rn(__fadd_rn(er[2 * 1024 + e0 + e_l], acc[rt][2][i]), bh4[2]);
      float g3 = __fadd_rn(__fadd_rn(er[3 * 1024 + e0 + e_l], acc[rt][3][i]), bh4[3]);
      float ig = 1.0f / (1.0f + expf(-g0));
      float fg = 1.0f / (1.0f + expf(-g1));
      float gg = tanhf(g2);
      float og = 1.0f / (1.0f + expf(-g3));
      float co = eC[rl * 33 + e_l];
      float cn = __fadd_rn(__fmul_rn(fg, co), __fmul_rn(ig, gg));
      float hn = __fmul_rn(og, tanhf(cn));
      eC[rl * 33 + e_l] = cn;
      eH[rl * 33 + e_l] = hn;
    }
    __syncthreads();
    // phase 3: coalesced store c + h-splits
    {
      int r = l >> 3, ch = l & 7;
#pragma unroll
      for (int q = 0; q < 4; q++) {
        int rr2 = r + q * 8;
        size_t gb = (size_t)(rowbase + rr2) * EE + e0 + ch * 4;
        *(float4*)(cbuf + gb) = *(const float4*)(eC + rr2 * 33 + ch * 4);
        float4 hv = *(const float4*)(eH + rr2 * 33 + ch * 4);
        float hf2[4] = {hv.x, hv.y, hv.z, hv.w};
        bf16x4 o0, o1, o2;
#pragma unroll
        for (int jj = 0; jj < 4; jj++) {
          __bf16 a = (__bf16)hf2[jj]; float r1 = hf2[jj] - (float)a;
          __bf16 b = (__bf16)r1;      float r2 = r1 - (float)b;
          o0[jj] = a; o1[jj] = b; o2[jj] = (__bf16)r2;
        }
        *(bf16x4*)(hN0 + gb) = o0;
        *(bf16x4*)(hN1 + gb) = o1;
        *(bf16x4*)(hN2 + gb) = o2;
      }
    }
    __syncthreads();
  }
}

// ---------------- fallback fp32 LSTM step (proven path) ----------------
__global__ __launch_bounds__(256, 4)
void lstm_step_kernel(const float* __restrict__ hin, float* __restrict__ hout,
                      float* __restrict__ cbuf, const float* __restrict__ Whh,
                      const float* __restrict__ embW, const float* __restrict__ bhh,
                      const int* __restrict__ tok, int step) {
  __shared__ float hs[32][132];
  __shared__ float ws[32][132];
  const int row0 = blockIdx.x * 128;
  const int e0 = blockIdx.y * 32;
  const int tid = threadIdx.x;
  const int tx = tid & 15, ty = tid >> 4;
  float acc[8][4][2];
#pragma unroll
  for (int r = 0; r < 8; r++)
#pragma unroll
    for (int g = 0; g < 4; g++) { acc[r][g][0] = 0.0f; acc[r][g][1] = 0.0f; }

  const int lr = tid >> 3, lk = (tid & 7) * 4;
  for (int k0 = 0; k0 < EE; k0 += 32) {
#pragma unroll
    for (int rr = 0; rr < 4; rr++) {
      int row = lr + rr * 32;
      float4 v = *reinterpret_cast<const float4*>(hin + (size_t)(row0 + row) * EE + k0 + lk);
      hs[lk + 0][row] = v.x; hs[lk + 1][row] = v.y; hs[lk + 2][row] = v.z; hs[lk + 3][row] = v.w;
      int cg = row;
      int j = (cg >> 5) * 1024 + e0 + (cg & 31);
      float4 u = *reinterpret_cast<const float4*>(Whh + (size_t)j * EE + k0 + lk);
      ws[lk + 0][cg] = u.x; ws[lk + 1][cg] = u.y; ws[lk + 2][cg] = u.z; ws[lk + 3][cg] = u.w;
    }
    __syncthreads();
#pragma unroll
    for (int k = 0; k < 32; k++) {
      float4 va = *reinterpret_cast<const float4*>(&hs[k][ty * 8]);
      float4 vb = *reinterpret_cast<const float4*>(&hs[k][ty * 8 + 4]);
      float a0[8] = {va.x, va.y, va.z, va.w, vb.x, vb.y, vb.z, vb.w};
      float wvv[4][2];
#pragma unroll
      for (int g = 0; g < 4; g++) {
        float2 f2 = *reinterpret_cast<const float2*>(&ws[k][g * 32 + tx * 2]);
        wvv[g][0] = f2.x; wvv[g][1] = f2.y;
      }
#pragma unroll
      for (int r = 0; r < 8; r++)
#pragma unroll
        for (int g = 0; g < 4; g++) {
          acc[r][g][0] = fmaf(a0[r], wvv[g][0], acc[r][g][0]);
          acc[r][g][1] = fmaf(a0[r], wvv[g][1], acc[r][g][1]);
        }
    }
    __syncthreads();
  }
#pragma unroll
  for (int r = 0; r < 8; r++) {
    int b = row0 + ty * 8 + r;
    int tk = (step == 0) ? 0 : tok[b];
    const float* er = embW + (size_t)tk * GG;
#pragma unroll
    for (int x = 0; x < 2; x++) {
      int e = e0 + tx * 2 + x;
      float gate[4];
#pragma unroll
      for (int g = 0; g < 4; g++) {
        int j = g * 1024 + e;
        gate[g] = __fadd_rn(__fadd_rn(er[j], acc[r][g][x]), bhh[j]);
      }
      float ig = 1.0f / (1.0f + expf(-gate[0]));
      float fg = 1.0f / (1.0f + expf(-gate[1]));
      float gg = tanhf(gate[2]);
      float og = 1.0f / (1.0f + expf(-gate[3]));
      size_t idx = (size_t)b * EE + e;
      float cn;
      if (step == 0) cn = __fadd_rn(0.0f, __fmul_rn(ig, gg));
      else           cn = __fadd_rn(__fmul_rn(fg, cbuf[idx]), __fmul_rn(ig, gg));
      cbuf[idx] = cn;
      hout[idx] = __fmul_rn(og, tanhf(cn));
    }
  }
}

// ---------------- logits + softmax + gumbel sampling ----------------
template <int HS>
__global__ __launch_bounds__(256)
void sample_kernel_t(const float* __restrict__ hf,
                     const __bf16* __restrict__ h0s, const __bf16* __restrict__ h1s,
                     const __bf16* __restrict__ h2s,
                     const float* __restrict__ W1, const float* __restrict__ b1,
                     int* __restrict__ tok, float* __restrict__ out,
                     float* __restrict__ ent_acc, int* __restrict__ match_acc,
                     int step, unsigned key0, unsigned key1) {
  __shared__ float hsm[64][36];
  __shared__ float wsm[64][65];
  __shared__ float entLds[4];
  __shared__ int   mLds[4];
  const int row0 = blockIdx.x * 32;
  const int tid = threadIdx.x;
  const int wv = tid >> 6, lane = tid & 63;
  float acc[8];
#pragma unroll
  for (int r = 0; r < 8; r++) acc[r] = 0.0f;

  for (int k0 = 0; k0 < EE; k0 += 64) {
    {
      int row = tid >> 3, kb = (tid & 7) * 8;
      if (HS) {
        size_t g = (size_t)(row0 + row) * EE + k0 + kb;
        bf16x8 u0 = *(const bf16x8*)(h0s + g);
        bf16x8 u1 = *(const bf16x8*)(h1s + g);
        bf16x8 u2 = *(const bf16x8*)(h2s + g);
#pragma unroll
        for (int j = 0; j < 8; j++)
          hsm[kb + j][row] = __fadd_rn(__fadd_rn((float)u0[j], (float)u1[j]), (float)u2[j]);
      } else {
        const float4* p = reinterpret_cast<const float4*>(hf + (size_t)(row0 + row) * EE + k0 + kb);
        float4 v0 = p[0], v1 = p[1];
        hsm[kb + 0][row] = v0.x; hsm[kb + 1][row] = v0.y; hsm[kb + 2][row] = v0.z; hsm[kb + 3][row] = v0.w;
        hsm[kb + 4][row] = v1.x; hsm[kb + 5][row] = v1.y; hsm[kb + 6][row] = v1.z; hsm[kb + 7][row] = v1.w;
      }
      int tr = tid >> 2, kc = (tid & 3) * 16;
      const float4* q = reinterpret_cast<const float4*>(W1 + (size_t)tr * EE + k0 + kc);
#pragma unroll
      for (int i = 0; i < 4; i++) {
        float4 a = q[i];
        wsm[tr][kc + i * 4 + 0] = a.x; wsm[tr][kc + i * 4 + 1] = a.y;
        wsm[tr][kc + i * 4 + 2] = a.z; wsm[tr][kc + i * 4 + 3] = a.w;
      }
    }
    __syncthreads();
#pragma unroll
    for (int k = 0; k < 64; k++) {
      float w0 = wsm[lane][k];
      float4 va = *reinterpret_cast<const float4*>(&hsm[k][wv * 8]);
      float4 vb = *reinterpret_cast<const float4*>(&hsm[k][wv * 8 + 4]);
      acc[0] = fmaf(va.x, w0, acc[0]); acc[1] = fmaf(va.y, w0, acc[1]);
      acc[2] = fmaf(va.z, w0, acc[2]); acc[3] = fmaf(va.w, w0, acc[3]);
      acc[4] = fmaf(vb.x, w0, acc[4]); acc[5] = fmaf(vb.y, w0, acc[5]);
      acc[6] = fmaf(vb.z, w0, acc[6]); acc[7] = fmaf(vb.w, w0, acc[7]);
    }
    __syncthreads();
  }

  const float b1v = b1[lane];
  float entLane = 0.0f;
  int mcnt = 0;
#pragma unroll 1
  for (int r = 0; r < 8; r++) {
    int b = row0 + wv * 8 + r;
    float lg = __fadd_rn(acc[r], b1v);
    float mx = wave_max64(lg);
    float e = expf(lg - mx);
    float s = wave_sum64(e);
    float p = e / s;
    float gv; int gi; wave_argmax64(p, lane, gv, gi);
    unsigned nidx = (unsigned)(b * 64 + lane);
    unsigned o0, o1, bits;
#if PRNG_PARTITIONABLE
    tf2x32(key0, key1, 0u, nidx, o0, o1);
    bits = o0 ^ o1;
#else
    const unsigned HALF = (BB * TTK) / 2;
    if (nidx < HALF) { tf2x32(key0, key1, nidx, nidx + HALF, o0, o1); bits = o0; }
    else             { tf2x32(key0, key1, nidx - HALF, nidx, o0, o1); bits = o1; }
#endif
    float f = __uint_as_float((bits >> 9) | 0x3f800000u) - 1.0f;
    float u = fmaxf(1.17549435e-38f, f);
    float gum = -logf(-logf(u));
    float z = __fadd_rn(gum, lg);
    float zv; int zi; wave_argmax64(z, lane, zv, zi);
    float pa = __shfl(p, zi);
    if (lane == 0) {
      out[step * BB + b] = logf(pa);
      out[BB * LLEN + b * LLEN + step] = (float)zi;
      tok[b] = zi;
      if (gi == zi) mcnt++;
    }
    float pp = p + 1e-8f;
    entLane += pp * logf(pp);
  }
  float esum = wave_sum64(entLane);
  if (lane == 0) { entLds[wv] = esum; mLds[wv] = mcnt; }
  __syncthreads();
  if (tid == 0) {
    atomicAdd(ent_acc, entLds[0] + entLds[1] + entLds[2] + entLds[3]);
    atomicAdd(match_acc, mLds[0] + mLds[1] + mLds[2] + mLds[3]);
  }
}

__global__ void finalize_kernel(float* __restrict__ out,
                                const float* __restrict__ ent_acc,
                                const int* __restrict__ match_acc) {
  if (threadIdx.x == 0) {
    out[2 * BB * LLEN + 0] = -(*ent_acc);
    out[2 * BB * LLEN + 1] = (float)(*match_acc);
    out[2 * BB * LLEN + 2] = (float)(BB * LLEN);
  }
}

extern "C" void kernel_launch(void* const* d_in, const int* in_sizes, int n_in,
                              void* d_out, int out_size, void* d_ws, size_t ws_size,
                              hipStream_t stream) {
  const float* h_t = (const float*)d_in[0];
  const float* emb = (const float*)d_in[2];
  const float* Wih = (const float*)d_in[3];
  const float* Whh = (const float*)d_in[4];
  const float* bih = (const float*)d_in[5];
  const float* bhh = (const float*)d_in[6];
  const float* W1  = (const float*)d_in[7];
  const float* b1  = (const float*)d_in[8];
  float* out = (float*)d_out;

  // per-step keys
  unsigned k0s[LLEN], k1s[LLEN];
#if PRNG_PARTITIONABLE
  for (int s = 0; s < LLEN; s++) {
    unsigned a, b2; tf2x32(0u, 42u, 0u, (unsigned)s, a, b2);
    k0s[s] = a; k1s[s] = b2;
  }
#else
  {
    unsigned bitsArr[40];
    for (int j = 0; j < 20; j++) {
      unsigned a, b2; tf2x32(0u, 42u, (unsigned)j, (unsigned)(j + 20), a, b2);
      bitsArr[j] = a; bitsArr[20 + j] = b2;
    }
    for (int s = 0; s < LLEN; s++) { k0s[s] = bitsArr[2 * s]; k1s[s] = bitsArr[2 * s + 1]; }
  }
#endif

  const size_t NE = (size_t)BB * EE;          // 8,388,608
  const size_t WN = (size_t)GG * EE;          // 4,194,304
  const size_t NEED = NE * 4 + 6 * NE * 2 + 3 * WN * 2 + (size_t)TTK * GG * 4 + BB * 4 + 64;

  if (ws_size >= NEED) {
    // ---------------- MFMA path ----------------
    char* p = (char*)d_ws;
    float*  cbuf = (float*)p;            p += NE * 4;
    __bf16* hA0  = (__bf16*)p;           p += NE * 2;
    __bf16* hA1  = (__bf16*)p;           p += NE * 2;
    __bf16* hA2  = (__bf16*)p;           p += NE * 2;
    __bf16* hB0  = (__bf16*)p;           p += NE * 2;
    __bf16* hB1  = (__bf16*)p;           p += NE * 2;
    __bf16* hB2  = (__bf16*)p;           p += NE * 2;
    __bf16* w0   = (__bf16*)p;           p += WN * 2;
    __bf16* w1   = (__bf16*)p;           p += WN * 2;
    __bf16* w2   = (__bf16*)p;           p += WN * 2;
    float*  embW = (float*)p;            p += (size_t)TTK * GG * 4;
    int*    tok  = (int*)p;              p += BB * 4;
    float*  ent_acc = (float*)p;
    int*    match_acc = (int*)(p + 4);

    hipLaunchKernelGGL(split3_kernel, dim3(512), dim3(256), 0, stream,
                       h_t, hA0, hA1, hA2, (int)NE);
    hipLaunchKernelGGL(split3_kernel, dim3(512), dim3(256), 0, stream,
                       Whh, w0, w1, w2, (int)WN);
    hipLaunchKernelGGL(embw_kernel, dim3(128), dim3(256), 0, stream,
                       emb, Wih, bih, embW, ent_acc, match_acc);
    for (int s = 0; s < LLEN; s++) {
      const __bf16 *r0 = (s & 1) ? hB0 : hA0, *r1 = (s & 1) ? hB1 : hA1, *r2 = (s & 1) ? hB2 : hA2;
      __bf16 *n0 = (s & 1) ? hA0 : hB0, *n1 = (s & 1) ? hA1 : hB1, *n2 = (s & 1) ? hA2 : hB2;
      hipLaunchKernelGGL(lstm_mfma_kernel, dim3(1024), dim3(256), 0, stream,
                         r0, r1, r2, n0, n1, n2, cbuf, w0, w1, w2, embW, bhh, tok, s);
      hipLaunchKernelGGL((sample_kernel_t<1>), dim3(256), dim3(256), 0, stream,
                         (const float*)nullptr, n0, n1, n2, W1, b1, tok, out,
                         ent_acc, match_acc, s, k0s[s], k1s[s]);
    }
    hipLaunchKernelGGL(finalize_kernel, dim3(1), dim3(64), 0, stream,
                       out, ent_acc, match_acc);
  } else {
    // ---------------- fallback fp32 path ----------------
    float* ws = (float*)d_ws;
    float* h0   = ws;
    float* h1   = ws + NE;
    float* cbuf = ws + 2 * NE;
    float* embW = ws + 3 * NE;
    int*   tok  = (int*)(ws + 3 * NE + (size_t)TTK * GG);
    float* ent_acc = (float*)(tok + BB);
    int*   match_acc = (int*)(ent_acc + 1);

    hipLaunchKernelGGL(embw_kernel, dim3(128), dim3(256), 0, stream,
                       emb, Wih, bih, embW, ent_acc, match_acc);
    for (int s = 0; s < LLEN; s++) {
      const float* hin = (s == 0) ? h_t : ((s & 1) ? h0 : h1);
      float* hout = (s & 1) ? h1 : h0;
      hipLaunchKernelGGL(lstm_step_kernel, dim3(64, 32), dim3(256), 0, stream,
                         hin, hout, cbuf, Whh, embW, bhh, tok, s);
      hipLaunchKernelGGL((sample_kernel_t<0>), dim3(256), dim3(256), 0, stream,
                         hout, (const __bf16*)nullptr, (const __bf16*)nullptr,
                         (const __bf16*)nullptr, W1, b1, tok, out,
                         ent_acc, match_acc, s, k0s[s], k1s[s]);
    }
    hipLaunchKernelGGL(finalize_kernel, dim3(1), dim3(64), 0, stream,
                       out, ent_acc, match_acc);
  }
}

// Round 13
// 8780.524 us; speedup vs baseline: 1.0973x; 1.0973x over previous
//
#include <hip/hip_runtime.h>
#include <hip/hip_bf16.h>
#include <stdint.h>
#include <math.h>

#define BB   8192
#define EE   1024
#define GG   4096
#define TTK  64
#define LLEN 20

#define PRNG_PARTITIONABLE 1

typedef __attribute__((ext_vector_type(8)))  __bf16 bf16x8;
typedef __attribute__((ext_vector_type(4)))  __bf16 bf16x4;
typedef __attribute__((ext_vector_type(16))) float  f32x16;

// ---------------- Threefry-2x32 ----------------
__host__ __device__ __forceinline__ void tf2x32(unsigned k0, unsigned k1,
                                                unsigned x0, unsigned x1,
                                                unsigned& o0, unsigned& o1) {
  unsigned ks2 = k0 ^ k1 ^ 0x1BD11BDAu;
#define TFR(r) { x0 += x1; x1 = (x1 << (r)) | (x1 >> (32 - (r))); x1 ^= x0; }
  x0 += k0; x1 += k1;
  TFR(13) TFR(15) TFR(26) TFR(6)  x0 += k1;  x1 += ks2 + 1u;
  TFR(17) TFR(29) TFR(16) TFR(24) x0 += ks2; x1 += k0 + 2u;
  TFR(13) TFR(15) TFR(26) TFR(6)  x0 += k0;  x1 += k1 + 3u;
  TFR(17) TFR(29) TFR(16) TFR(24) x0 += k1;  x1 += ks2 + 4u;
  TFR(13) TFR(15) TFR(26) TFR(6)  x0 += ks2; x1 += k0 + 5u;
#undef TFR
  o0 = x0; o1 = x1;
}

// ---------------- wave-64 reductions ----------------
__device__ __forceinline__ float wave_max64(float v) {
#pragma unroll
  for (int o = 32; o > 0; o >>= 1) v = fmaxf(v, __shfl_xor(v, o));
  return v;
}
__device__ __forceinline__ float wave_sum64(float v) {
#pragma unroll
  for (int o = 32; o > 0; o >>= 1) v += __shfl_xor(v, o);
  return v;
}
__device__ __forceinline__ void wave_argmax64(float v, int i, float& rv, int& ri) {
  rv = v; ri = i;
#pragma unroll
  for (int o = 32; o > 0; o >>= 1) {
    float ov = __shfl_xor(rv, o);
    int   oi = __shfl_xor(ri, o);
    if (ov > rv || (ov == rv && oi < ri)) { rv = ov; ri = oi; }
  }
}

// global -> LDS direct DMA, 16B per lane
__device__ __forceinline__ void gl16(const __bf16* g, __bf16* l) {
  __builtin_amdgcn_global_load_lds(
      (const __attribute__((address_space(1))) void*)g,
      (__attribute__((address_space(3))) void*)l, 16, 0, 0);
}

// ---------------- fp32 -> 3x bf16 split ----------------
__global__ void split3_kernel(const float* __restrict__ in, __bf16* __restrict__ s0,
                              __bf16* __restrict__ s1, __bf16* __restrict__ s2, int n) {
  int i = blockIdx.x * blockDim.x + threadIdx.x;
  int stride = gridDim.x * blockDim.x;
  for (; i < n; i += stride) {
    float x = in[i];
    __bf16 a = (__bf16)x; float r1 = x - (float)a;
    __bf16 b = (__bf16)r1; float r2 = r1 - (float)b;
    s0[i] = a; s1[i] = b; s2[i] = (__bf16)r2;
  }
}

// ---------------- embW[t][j] = dot(emb[t], W_ih[j]) + b_ih[j] ----------------
__global__ __launch_bounds__(256)
void embw_kernel(const float* __restrict__ emb, const float* __restrict__ Wih,
                 const float* __restrict__ bih, float* __restrict__ embW,
                 float* __restrict__ ent_acc, int* __restrict__ match_acc) {
  if (blockIdx.x == 0 && threadIdx.x == 0) { *ent_acc = 0.0f; *match_acc = 0; }
  __shared__ float hsm[64][36];
  __shared__ float wsm[64][65];
  const int j0 = blockIdx.x * 32;
  const int tid = threadIdx.x;
  const int wv = tid >> 6, lane = tid & 63;
  float acc[8];
#pragma unroll
  for (int r = 0; r < 8; r++) acc[r] = 0.0f;

  for (int k0 = 0; k0 < EE; k0 += 64) {
    {
      int row = tid >> 3, kb = (tid & 7) * 8;
      const float4* p = reinterpret_cast<const float4*>(Wih + (size_t)(j0 + row) * EE + k0 + kb);
      float4 v0 = p[0], v1 = p[1];
      hsm[kb + 0][row] = v0.x; hsm[kb + 1][row] = v0.y; hsm[kb + 2][row] = v0.z; hsm[kb + 3][row] = v0.w;
      hsm[kb + 4][row] = v1.x; hsm[kb + 5][row] = v1.y; hsm[kb + 6][row] = v1.z; hsm[kb + 7][row] = v1.w;
      int tr = tid >> 2, kc = (tid & 3) * 16;
      const float4* q = reinterpret_cast<const float4*>(emb + (size_t)tr * EE + k0 + kc);
#pragma unroll
      for (int i = 0; i < 4; i++) {
        float4 a = q[i];
        wsm[tr][kc + i * 4 + 0] = a.x; wsm[tr][kc + i * 4 + 1] = a.y;
        wsm[tr][kc + i * 4 + 2] = a.z; wsm[tr][kc + i * 4 + 3] = a.w;
      }
    }
    __syncthreads();
#pragma unroll
    for (int k = 0; k < 64; k++) {
      float w0 = wsm[lane][k];
      float4 va = *reinterpret_cast<const float4*>(&hsm[k][wv * 8]);
      float4 vb = *reinterpret_cast<const float4*>(&hsm[k][wv * 8 + 4]);
      acc[0] = fmaf(va.x, w0, acc[0]); acc[1] = fmaf(va.y, w0, acc[1]);
      acc[2] = fmaf(va.z, w0, acc[2]); acc[3] = fmaf(va.w, w0, acc[3]);
      acc[4] = fmaf(vb.x, w0, acc[4]); acc[5] = fmaf(vb.y, w0, acc[5]);
      acc[6] = fmaf(vb.z, w0, acc[6]); acc[7] = fmaf(vb.w, w0, acc[7]);
    }
    __syncthreads();
  }
#pragma unroll
  for (int r = 0; r < 8; r++) {
    int j = j0 + wv * 8 + r;
    embW[(size_t)lane * GG + j] = __fadd_rn(acc[r], bih[j]);
  }
}

// ---------------- MFMA LSTM step (bf16x3 fp32 emulation) ----------------
// Round-10 structure (single 80KB buffer, 2 blocks/CU, DMA staging, raw
// barriers with counted waits) + (4m x 2n) XCD tiling (cuts B refetch) +
// setprio around the MFMA phase. Empirical best of the session.
#define AST   104     // elems per row (208 B = 13 chunks)
#define BUFE  39936   // elems (79,872 B)
__global__ __launch_bounds__(256, 2)
void lstm_mfma_kernel(const __bf16* __restrict__ hA0, const __bf16* __restrict__ hA1,
                      const __bf16* __restrict__ hA2,
                      __bf16* __restrict__ hN0, __bf16* __restrict__ hN1,
                      __bf16* __restrict__ hN2,
                      float* __restrict__ cbuf,
                      const __bf16* __restrict__ w0s, const __bf16* __restrict__ w1s,
                      const __bf16* __restrict__ w2s,
                      const float* __restrict__ embW, const float* __restrict__ bhh,
                      const int* __restrict__ tok, int step) {
  __shared__ __bf16 lds[BUFE];   // 79,872 B -> 2 blocks/CU
  // XCD tiling: xcd = bid&7 -> (xm, xn) in 4x2; each XCD owns 8 m x 16 n.
  unsigned bid = blockIdx.x;
  unsigned xcd = bid & 7, j = bid >> 3;        // j in [0,128)
  unsigned xm = xcd >> 1, xn = xcd & 1;
  const int m = (int)(xm * 8 + (j & 7));
  const int n = (int)(xn * 16 + (j >> 3));
  const int row0 = m * 256, e0 = n * 32;
  const int tid = threadIdx.x;
  const int w = tid >> 6, l = tid & 63;

  f32x16 acc[2][4];
#pragma unroll
  for (int rt = 0; rt < 2; rt++)
#pragma unroll
    for (int ct = 0; ct < 4; ct++)
#pragma unroll
      for (int q = 0; q < 16; q++) acc[rt][ct][q] = 0.0f;

  // ---- per-lane DMA source addresses (slot decode; done once) ----
  const __bf16* aSrcP[13];
  const __bf16* bSrcP[7];
  const int nB = (w < 2) ? 7 : 6;
#pragma unroll
  for (int i = 0; i < 13; i++) {
    int slot = (w * 13 + i) * 64 + l;
    int row = slot / 13, chk = slot - row * 13;
    const __bf16* base;
    size_t off;
    if (chk < 12) {
      int s = chk >> 2, q = chk & 3;
      base = (s == 0) ? hA0 : (s == 1) ? hA1 : hA2;
      off = (size_t)(row0 + row) * EE + q * 8;
    } else { base = hA0; off = 0; }
    aSrcP[i] = base + off;
  }
#pragma unroll
  for (int i = 0; i < 7; i++) {
    if (i < nB) {
      int ib = w + i * 4;
      int slot = ib * 64 + l;
      int c = slot / 13, chk = slot - c * 13;
      const __bf16* base;
      size_t off;
      if (chk < 12) {
        int s = chk >> 2, q = chk & 3;
        int jj = (c >> 5) * 1024 + e0 + (c & 31);
        base = (s == 0) ? w0s : (s == 1) ? w1s : w2s;
        off = (size_t)jj * EE + q * 8;
      } else { base = w0s; off = 0; }
      bSrcP[i] = base + off;
    }
  }
  const int aDstOff = w * 13 * 512;            // elems
  const int bDstOff = 26624 + w * 512;         // elems (53248 B base)

#define STAGE(KE) do {                                                   \
    _Pragma("unroll")                                                    \
    for (int i_ = 0; i_ < 13; i_++)                                      \
      gl16(aSrcP[i_] + (KE), lds + aDstOff + i_ * 512);                  \
    _Pragma("unroll")                                                    \
    for (int i_ = 0; i_ < 7; i_++)                                       \
      if (i_ < nB) gl16(bSrcP[i_] + (KE), lds + bDstOff + i_ * 2048);    \
  } while (0)

  // fragment read bases
  const __bf16* aB = lds + (w * 64 + (l & 31)) * AST + (l >> 5) * 8;
  const __bf16* bB = lds + (256 + (l & 31)) * AST + (l >> 5) * 8;

  for (int kt = 0; kt < 32; ++kt) {
    // ---- stage this K-tile via DMA; sibling block's MFMAs cover the wait ----
    STAGE(kt * 32);
    asm volatile("s_waitcnt vmcnt(0)" ::: "memory");
    __builtin_amdgcn_s_barrier();
    // ---- compute (interleaved, minimal live registers) ----
    __builtin_amdgcn_s_setprio(1);
#pragma unroll
    for (int kh = 0; kh < 2; kh++) {
      bf16x8 a[2][3];
#pragma unroll
      for (int rt = 0; rt < 2; rt++)
#pragma unroll
        for (int s = 0; s < 3; s++)
          a[rt][s] = *(const bf16x8*)(aB + rt * 32 * AST + s * 32 + kh * 16);
#pragma unroll
      for (int ct = 0; ct < 4; ct++) {
        bf16x8 b0 = *(const bf16x8*)(bB + ct * 32 * AST + 0  + kh * 16);
        bf16x8 b1 = *(const bf16x8*)(bB + ct * 32 * AST + 32 + kh * 16);
        bf16x8 b2 = *(const bf16x8*)(bB + ct * 32 * AST + 64 + kh * 16);
#pragma unroll
        for (int rt = 0; rt < 2; rt++) {
          f32x16 t = acc[rt][ct];
          t = __builtin_amdgcn_mfma_f32_32x32x16_bf16(a[rt][2], b0, t, 0, 0, 0);
          t = __builtin_amdgcn_mfma_f32_32x32x16_bf16(a[rt][0], b2, t, 0, 0, 0);
          t = __builtin_amdgcn_mfma_f32_32x32x16_bf16(a[rt][1], b1, t, 0, 0, 0);
          t = __builtin_amdgcn_mfma_f32_32x32x16_bf16(a[rt][1], b0, t, 0, 0, 0);
          t = __builtin_amdgcn_mfma_f32_32x32x16_bf16(a[rt][0], b1, t, 0, 0, 0);
          t = __builtin_amdgcn_mfma_f32_32x32x16_bf16(a[rt][0], b0, t, 0, 0, 0);
          acc[rt][ct] = t;
        }
      }
    }
    __builtin_amdgcn_s_setprio(0);
    // all reads landed in regs; next STAGE may overwrite after the barrier
    asm volatile("s_waitcnt lgkmcnt(0)" ::: "memory");
    __builtin_amdgcn_s_barrier();
  }
#undef STAGE

  // ---- epilogue: LSTM cell, via per-wave LDS transpose patches ----
  float* eC = ((float*)lds) + w * 2112;   // [32][33]
  float* eH = eC + 1056;                  // [32][33]
  const int e_l = l & 31, half = l >> 5;
  float bh4[4];
#pragma unroll
  for (int g = 0; g < 4; g++) bh4[g] = bhh[g * 1024 + e0 + e_l];

#pragma unroll
  for (int rt = 0; rt < 2; rt++) {
    const int rowbase = row0 + w * 64 + rt * 32;
    // phase 1: stage c_old (coalesced) into LDS
    {
      int r = l >> 3, ch = l & 7;
#pragma unroll
      for (int q = 0; q < 4; q++) {
        float4 cv;
        if (step == 0) cv = make_float4(0.f, 0.f, 0.f, 0.f);
        else cv = *(const float4*)(cbuf + (size_t)(rowbase + r + q * 8) * EE + e0 + ch * 4);
        *(float4*)(eC + (r + q * 8) * 33 + ch * 4) = cv;
      }
    }
    __syncthreads();
    // phase 2: per-lane cell computation
#pragma unroll
    for (int i = 0; i < 16; i++) {
      int rl = (i & 3) + 8 * (i >> 2) + 4 * half;
      int b = rowbase + rl;
      int tk = (step == 0) ? 0 : tok[b];
      const float* er = embW + (size_t)tk * GG;
      float g0 = __fadd_rn(__fadd_rn(er[0 * 1024 + e0 + e_l], acc[rt][0][i]), bh4[0]);
      float g1 = __fadd_rn(__fadd_rn(er[1 * 1024 + e0 + e_l], acc[rt][1][i]), bh4[1]);
      float g2 = __fadd_rn(__fadd_rn(er[2 * 1024 + e0 + e_l], acc[rt][2][i]), bh4[2]);
      float g3 = __fadd_rn(__fadd_rn(er[3 * 1024 + e0 + e_l], acc[rt][3][i]), bh4[3]);
      float ig = 1.0f / (1.0f + expf(-g0));
      float fg = 1.0f / (1.0f + expf(-g1));
      float gg = tanhf(g2);
      float og = 1.0f / (1.0f + expf(-g3));
      float co = eC[rl * 33 + e_l];
      float cn = __fadd_rn(__fmul_rn(fg, co), __fmul_rn(ig, gg));
      float hn = __fmul_rn(og, tanhf(cn));
      eC[rl * 33 + e_l] = cn;
      eH[rl * 33 + e_l] = hn;
    }
    __syncthreads();
    // phase 3: coalesced store c + h-splits
    {
      int r = l >> 3, ch = l & 7;
#pragma unroll
      for (int q = 0; q < 4; q++) {
        int rr2 = r + q * 8;
        size_t gb = (size_t)(rowbase + rr2) * EE + e0 + ch * 4;
        *(float4*)(cbuf + gb) = *(const float4*)(eC + rr2 * 33 + ch * 4);
        float4 hv = *(const float4*)(eH + rr2 * 33 + ch * 4);
        float hf[4] = {hv.x, hv.y, hv.z, hv.w};
        bf16x4 o0, o1, o2;
#pragma unroll
        for (int jj = 0; jj < 4; jj++) {
          __bf16 a = (__bf16)hf[jj]; float r1 = hf[jj] - (float)a;
          __bf16 b = (__bf16)r1;     float r2 = r1 - (float)b;
          o0[jj] = a; o1[jj] = b; o2[jj] = (__bf16)r2;
        }
        *(bf16x4*)(hN0 + gb) = o0;
        *(bf16x4*)(hN1 + gb) = o1;
        *(bf16x4*)(hN2 + gb) = o2;
      }
    }
    __syncthreads();
  }
}

// ---------------- fallback fp32 LSTM step (proven path) ----------------
__global__ __launch_bounds__(256, 4)
void lstm_step_kernel(const float* __restrict__ hin, float* __restrict__ hout,
                      float* __restrict__ cbuf, const float* __restrict__ Whh,
                      const float* __restrict__ embW, const float* __restrict__ bhh,
                      const int* __restrict__ tok, int step) {
  __shared__ float hs[32][132];
  __shared__ float ws[32][132];
  const int row0 = blockIdx.x * 128;
  const int e0 = blockIdx.y * 32;
  const int tid = threadIdx.x;
  const int tx = tid & 15, ty = tid >> 4;
  float acc[8][4][2];
#pragma unroll
  for (int r = 0; r < 8; r++)
#pragma unroll
    for (int g = 0; g < 4; g++) { acc[r][g][0] = 0.0f; acc[r][g][1] = 0.0f; }

  const int lr = tid >> 3, lk = (tid & 7) * 4;
  for (int k0 = 0; k0 < EE; k0 += 32) {
#pragma unroll
    for (int rr = 0; rr < 4; rr++) {
      int row = lr + rr * 32;
      float4 v = *reinterpret_cast<const float4*>(hin + (size_t)(row0 + row) * EE + k0 + lk);
      hs[lk + 0][row] = v.x; hs[lk + 1][row] = v.y; hs[lk + 2][row] = v.z; hs[lk + 3][row] = v.w;
      int cg = row;
      int j = (cg >> 5) * 1024 + e0 + (cg & 31);
      float4 u = *reinterpret_cast<const float4*>(Whh + (size_t)j * EE + k0 + lk);
      ws[lk + 0][cg] = u.x; ws[lk + 1][cg] = u.y; ws[lk + 2][cg] = u.z; ws[lk + 3][cg] = u.w;
    }
    __syncthreads();
#pragma unroll
    for (int k = 0; k < 32; k++) {
      float4 va = *reinterpret_cast<const float4*>(&hs[k][ty * 8]);
      float4 vb = *reinterpret_cast<const float4*>(&hs[k][ty * 8 + 4]);
      float a0[8] = {va.x, va.y, va.z, va.w, vb.x, vb.y, vb.z, vb.w};
      float wvv[4][2];
#pragma unroll
      for (int g = 0; g < 4; g++) {
        float2 f2 = *reinterpret_cast<const float2*>(&ws[k][g * 32 + tx * 2]);
        wvv[g][0] = f2.x; wvv[g][1] = f2.y;
      }
#pragma unroll
      for (int r = 0; r < 8; r++)
#pragma unroll
        for (int g = 0; g < 4; g++) {
          acc[r][g][0] = fmaf(a0[r], wvv[g][0], acc[r][g][0]);
          acc[r][g][1] = fmaf(a0[r], wvv[g][1], acc[r][g][1]);
        }
    }
    __syncthreads();
  }
#pragma unroll
  for (int r = 0; r < 8; r++) {
    int b = row0 + ty * 8 + r;
    int tk = (step == 0) ? 0 : tok[b];
    const float* er = embW + (size_t)tk * GG;
#pragma unroll
    for (int x = 0; x < 2; x++) {
      int e = e0 + tx * 2 + x;
      float gate[4];
#pragma unroll
      for (int g = 0; g < 4; g++) {
        int j = g * 1024 + e;
        gate[g] = __fadd_rn(__fadd_rn(er[j], acc[r][g][x]), bhh[j]);
      }
      float ig = 1.0f / (1.0f + expf(-gate[0]));
      float fg = 1.0f / (1.0f + expf(-gate[1]));
      float gg = tanhf(gate[2]);
      float og = 1.0f / (1.0f + expf(-gate[3]));
      size_t idx = (size_t)b * EE + e;
      float cn;
      if (step == 0) cn = __fadd_rn(0.0f, __fmul_rn(ig, gg));
      else           cn = __fadd_rn(__fmul_rn(fg, cbuf[idx]), __fmul_rn(ig, gg));
      cbuf[idx] = cn;
      hout[idx] = __fmul_rn(og, tanhf(cn));
    }
  }
}

// ---------------- logits + softmax + gumbel sampling ----------------
template <int HS>
__global__ __launch_bounds__(256)
void sample_kernel_t(const float* __restrict__ hf,
                     const __bf16* __restrict__ h0s, const __bf16* __restrict__ h1s,
                     const __bf16* __restrict__ h2s,
                     const float* __restrict__ W1, const float* __restrict__ b1,
                     int* __restrict__ tok, float* __restrict__ out,
                     float* __restrict__ ent_acc, int* __restrict__ match_acc,
                     int step, unsigned key0, unsigned key1) {
  __shared__ float hsm[64][36];
  __shared__ float wsm[64][65];
  __shared__ float entLds[4];
  __shared__ int   mLds[4];
  const int row0 = blockIdx.x * 32;
  const int tid = threadIdx.x;
  const int wv = tid >> 6, lane = tid & 63;
  float acc[8];
#pragma unroll
  for (int r = 0; r < 8; r++) acc[r] = 0.0f;

  for (int k0 = 0; k0 < EE; k0 += 64) {
    {
      int row = tid >> 3, kb = (tid & 7) * 8;
      if (HS) {
        size_t g = (size_t)(row0 + row) * EE + k0 + kb;
        bf16x8 u0 = *(const bf16x8*)(h0s + g);
        bf16x8 u1 = *(const bf16x8*)(h1s + g);
        bf16x8 u2 = *(const bf16x8*)(h2s + g);
#pragma unroll
        for (int j = 0; j < 8; j++)
          hsm[kb + j][row] = __fadd_rn(__fadd_rn((float)u0[j], (float)u1[j]), (float)u2[j]);
      } else {
        const float4* p = reinterpret_cast<const float4*>(hf + (size_t)(row0 + row) * EE + k0 + kb);
        float4 v0 = p[0], v1 = p[1];
        hsm[kb + 0][row] = v0.x; hsm[kb + 1][row] = v0.y; hsm[kb + 2][row] = v0.z; hsm[kb + 3][row] = v0.w;
        hsm[kb + 4][row] = v1.x; hsm[kb + 5][row] = v1.y; hsm[kb + 6][row] = v1.z; hsm[kb + 7][row] = v1.w;
      }
      int tr = tid >> 2, kc = (tid & 3) * 16;
      const float4* q = reinterpret_cast<const float4*>(W1 + (size_t)tr * EE + k0 + kc);
#pragma unroll
      for (int i = 0; i < 4; i++) {
        float4 a = q[i];
        wsm[tr][kc + i * 4 + 0] = a.x; wsm[tr][kc + i * 4 + 1] = a.y;
        wsm[tr][kc + i * 4 + 2] = a.z; wsm[tr][kc + i * 4 + 3] = a.w;
      }
    }
    __syncthreads();
#pragma unroll
    for (int k = 0; k < 64; k++) {
      float w0 = wsm[lane][k];
      float4 va = *reinterpret_cast<const float4*>(&hsm[k][wv * 8]);
      float4 vb = *reinterpret_cast<const float4*>(&hsm[k][wv * 8 + 4]);
      acc[0] = fmaf(va.x, w0, acc[0]); acc[1] = fmaf(va.y, w0, acc[1]);
      acc[2] = fmaf(va.z, w0, acc[2]); acc[3] = fmaf(va.w, w0, acc[3]);
      acc[4] = fmaf(vb.x, w0, acc[4]); acc[5] = fmaf(vb.y, w0, acc[5]);
      acc[6] = fmaf(vb.z, w0, acc[6]); acc[7] = fmaf(vb.w, w0, acc[7]);
    }
    __syncthreads();
  }

  const float b1v = b1[lane];
  float entLane = 0.0f;
  int mcnt = 0;
#pragma unroll 1
  for (int r = 0; r < 8; r++) {
    int b = row0 + wv * 8 + r;
    float lg = __fadd_rn(acc[r], b1v);
    float mx = wave_max64(lg);
    float e = expf(lg - mx);
    float s = wave_sum64(e);
    float p = e / s;
    float gv; int gi; wave_argmax64(p, lane, gv, gi);
    unsigned nidx = (unsigned)(b * 64 + lane);
    unsigned o0, o1, bits;
#if PRNG_PARTITIONABLE
    tf2x32(key0, key1, 0u, nidx, o0, o1);
    bits = o0 ^ o1;
#else
    const unsigned HALF = (BB * TTK) / 2;
    if (nidx < HALF) { tf2x32(key0, key1, nidx, nidx + HALF, o0, o1); bits = o0; }
    else             { tf2x32(key0, key1, nidx - HALF, nidx, o0, o1); bits = o1; }
#endif
    float f = __uint_as_float((bits >> 9) | 0x3f800000u) - 1.0f;
    float u = fmaxf(1.17549435e-38f, f);
    float gum = -logf(-logf(u));
    float z = __fadd_rn(gum, lg);
    float zv; int zi; wave_argmax64(z, lane, zv, zi);
    float pa = __shfl(p, zi);
    if (lane == 0) {
      out[step * BB + b] = logf(pa);
      out[BB * LLEN + b * LLEN + step] = (float)zi;
      tok[b] = zi;
      if (gi == zi) mcnt++;
    }
    float pp = p + 1e-8f;
    entLane += pp * logf(pp);
  }
  float esum = wave_sum64(entLane);
  if (lane == 0) { entLds[wv] = esum; mLds[wv] = mcnt; }
  __syncthreads();
  if (tid == 0) {
    atomicAdd(ent_acc, entLds[0] + entLds[1] + entLds[2] + entLds[3]);
    atomicAdd(match_acc, mLds[0] + mLds[1] + mLds[2] + mLds[3]);
  }
}

__global__ void finalize_kernel(float* __restrict__ out,
                                const float* __restrict__ ent_acc,
                                const int* __restrict__ match_acc) {
  if (threadIdx.x == 0) {
    out[2 * BB * LLEN + 0] = -(*ent_acc);
    out[2 * BB * LLEN + 1] = (float)(*match_acc);
    out[2 * BB * LLEN + 2] = (float)(BB * LLEN);
  }
}

extern "C" void kernel_launch(void* const* d_in, const int* in_sizes, int n_in,
                              void* d_out, int out_size, void* d_ws, size_t ws_size,
                              hipStream_t stream) {
  const float* h_t = (const float*)d_in[0];
  const float* emb = (const float*)d_in[2];
  const float* Wih = (const float*)d_in[3];
  const float* Whh = (const float*)d_in[4];
  const float* bih = (const float*)d_in[5];
  const float* bhh = (const float*)d_in[6];
  const float* W1  = (const float*)d_in[7];
  const float* b1  = (const float*)d_in[8];
  float* out = (float*)d_out;

  // per-step keys
  unsigned k0s[LLEN], k1s[LLEN];
#if PRNG_PARTITIONABLE
  for (int s = 0; s < LLEN; s++) {
    unsigned a, b2; tf2x32(0u, 42u, 0u, (unsigned)s, a, b2);
    k0s[s] = a; k1s[s] = b2;
  }
#else
  {
    unsigned bitsArr[40];
    for (int j = 0; j < 20; j++) {
      unsigned a, b2; tf2x32(0u, 42u, (unsigned)j, (unsigned)(j + 20), a, b2);
      bitsArr[j] = a; bitsArr[20 + j] = b2;
    }
    for (int s = 0; s < LLEN; s++) { k0s[s] = bitsArr[2 * s]; k1s[s] = bitsArr[2 * s + 1]; }
  }
#endif

  const size_t NE = (size_t)BB * EE;          // 8,388,608
  const size_t WN = (size_t)GG * EE;          // 4,194,304
  const size_t NEED = NE * 4 + 6 * NE * 2 + 3 * WN * 2 + (size_t)TTK * GG * 4 + BB * 4 + 64;

  if (ws_size >= NEED) {
    // ---------------- MFMA path ----------------
    char* p = (char*)d_ws;
    float*  cbuf = (float*)p;            p += NE * 4;
    __bf16* hA0  = (__bf16*)p;           p += NE * 2;
    __bf16* hA1  = (__bf16*)p;           p += NE * 2;
    __bf16* hA2  = (__bf16*)p;           p += NE * 2;
    __bf16* hB0  = (__bf16*)p;           p += NE * 2;
    __bf16* hB1  = (__bf16*)p;           p += NE * 2;
    __bf16* hB2  = (__bf16*)p;           p += NE * 2;
    __bf16* w0   = (__bf16*)p;           p += WN * 2;
    __bf16* w1   = (__bf16*)p;           p += WN * 2;
    __bf16* w2   = (__bf16*)p;           p += WN * 2;
    float*  embW = (float*)p;            p += (size_t)TTK * GG * 4;
    int*    tok  = (int*)p;              p += BB * 4;
    float*  ent_acc = (float*)p;
    int*    match_acc = (int*)(p + 4);

    hipLaunchKernelGGL(split3_kernel, dim3(512), dim3(256), 0, stream,
                       h_t, hA0, hA1, hA2, (int)NE);
    hipLaunchKernelGGL(split3_kernel, dim3(512), dim3(256), 0, stream,
                       Whh, w0, w1, w2, (int)WN);
    hipLaunchKernelGGL(embw_kernel, dim3(128), dim3(256), 0, stream,
                       emb, Wih, bih, embW, ent_acc, match_acc);
    for (int s = 0; s < LLEN; s++) {
      const __bf16 *r0 = (s & 1) ? hB0 : hA0, *r1 = (s & 1) ? hB1 : hA1, *r2 = (s & 1) ? hB2 : hA2;
      __bf16 *n0 = (s & 1) ? hA0 : hB0, *n1 = (s & 1) ? hA1 : hB1, *n2 = (s & 1) ? hA2 : hB2;
      hipLaunchKernelGGL(lstm_mfma_kernel, dim3(1024), dim3(256), 0, stream,
                         r0, r1, r2, n0, n1, n2, cbuf, w0, w1, w2, embW, bhh, tok, s);
      hipLaunchKernelGGL((sample_kernel_t<1>), dim3(256), dim3(256), 0, stream,
                         (const float*)nullptr, n0, n1, n2, W1, b1, tok, out,
                         ent_acc, match_acc, s, k0s[s], k1s[s]);
    }
    hipLaunchKernelGGL(finalize_kernel, dim3(1), dim3(64), 0, stream,
                       out, ent_acc, match_acc);
  } else {
    // ---------------- fallback fp32 path ----------------
    float* ws = (float*)d_ws;
    float* h0   = ws;
    float* h1   = ws + NE;
    float* cbuf = ws + 2 * NE;
    float* embW = ws + 3 * NE;
    int*   tok  = (int*)(ws + 3 * NE + (size_t)TTK * GG);
    float* ent_acc = (float*)(tok + BB);
    int*   match_acc = (int*)(ent_acc + 1);

    hipLaunchKernelGGL(embw_kernel, dim3(128), dim3(256), 0, stream,
                       emb, Wih, bih, embW, ent_acc, match_acc);
    for (int s = 0; s < LLEN; s++) {
      const float* hin = (s == 0) ? h_t : ((s & 1) ? h0 : h1);
      float* hout = (s & 1) ? h1 : h0;
      hipLaunchKernelGGL(lstm_step_kernel, dim3(64, 32), dim3(256), 0, stream,
                         hin, hout, cbuf, Whh, embW, bhh, tok, s);
      hipLaunchKernelGGL((sample_kernel_t<0>), dim3(256), dim3(256), 0, stream,
                         hout, (const __bf16*)nullptr, (const __bf16*)nullptr,
                         (const __bf16*)nullptr, W1, b1, tok, out,
                         ent_acc, match_acc, s, k0s[s], k1s[s]);
    }
    hipLaunchKernelGGL(finalize_kernel, dim3(1), dim3(64), 0, stream,
                       out, ent_acc, match_acc);
  }
}